// Round 17
// baseline (404.141 us; speedup 1.0000x reference)
//
#include <hip/hip_runtime.h>
#include <cstddef>
#include <cstdint>

typedef __attribute__((ext_vector_type(8))) short bf16x8;
typedef __attribute__((ext_vector_type(4))) float floatx4;
typedef __attribute__((ext_vector_type(2))) float v2f;

#define BSTRIDE 8192

// ---------------- pack helpers ----------------

__device__ __forceinline__ unsigned bf16pair(float a, float b) {
    unsigned ua = __float_as_uint(a), ub = __float_as_uint(b);
    ua += 0x7fffu + ((ua >> 16) & 1u);   // RNE
    ub += 0x7fffu + ((ub >> 16) & 1u);
    return (ua >> 16) | (ub & 0xffff0000u);
}
__device__ __forceinline__ unsigned short bf16one(float a) {
    unsigned ua = __float_as_uint(a);
    ua += 0x7fffu + ((ua >> 16) & 1u);
    return (unsigned short)(ua >> 16);
}

// ---------------- prep: bucket1 + wconv(W2,W3) + gemm1 (grid-split) ----------------

__global__ __launch_bounds__(256) void prep_k(
    const int* __restrict__ edge, unsigned* __restrict__ barr,
    int* __restrict__ bcnt, int E, int EA, int B1,
    const float* __restrict__ W2, unsigned short* __restrict__ Wt2,
    const float* __restrict__ W3, unsigned short* __restrict__ Wt3,
    const float* __restrict__ x, const float* __restrict__ W1,
    const float* __restrict__ a1s, const float* __restrict__ a1d,
    unsigned char* __restrict__ h8a, float* __restrict__ es,
    float* __restrict__ ed, int N) {
    int tid = threadIdx.x;
    if ((int)blockIdx.x < B1) {
        __shared__ int h[256];
        __shared__ int lbase[256];
        h[tid] = 0;
        __syncthreads();
        int start = blockIdx.x * 4096;
        unsigned ent[16];
        int lp[16];
#pragma unroll
        for (int k = 0; k < 16; ++k) {
            int i = start + k * 256 + tid;
            if (i < EA) {
                int s, d;
                if (i < E) { s = edge[i]; d = edge[E + i]; }
                else { s = i - E; d = s; }
                int b = d >> 8;
                ent[k] = (unsigned)s | ((unsigned)(d & 255) << 16) | ((unsigned)b << 24);
                lp[k] = atomicAdd(&h[b], 1);
            } else {
                ent[k] = 0xffffffffu;
                lp[k] = 0;
            }
        }
        __syncthreads();
        lbase[tid] = h[tid] ? atomicAdd(&bcnt[tid], h[tid]) : 0;
        __syncthreads();
#pragma unroll
        for (int k = 0; k < 16; ++k) {
            if (ent[k] != 0xffffffffu) {
                int b = ent[k] >> 24;
                int pos = lbase[b] + lp[k];
                if (pos < BSTRIDE)
                    barr[(size_t)b * BSTRIDE + pos] = ent[k] & 0x00ffffffu;
            }
        }
        return;
    }
    if ((int)blockIdx.x < B1 + 96) {
        int rel = blockIdx.x - B1;
        const float* W = (rel < 32) ? W2 : W3;
        unsigned short* Wt = (rel < 32) ? Wt2 : Wt3;
        int total = (rel < 32) ? 8192 : 16384;
        int o = ((rel < 32) ? rel : rel - 32) * 256 + tid;
        if (o < total) {
            int j = o & 7, lane = (o >> 3) & 63, ct = (o >> 9) & 7, ks = o >> 12;
            int k = ks * 32 + (lane >> 4) * 8 + j;
            int n = ct * 16 + (lane & 15);
            Wt[o] = bf16one(W[k * 128 + n]);
        }
        return;
    }
    int wave = tid >> 6, lane = tid & 63;
    int nbase = (blockIdx.x - B1 - 96) * 32;
    float w0 = W1[lane], w1 = W1[64 + lane];
    float as = a1s[lane], ad = a1d[lane];
    int head = lane >> 3;
#pragma unroll
    for (int it = 0; it < 8; ++it) {
        int n = nbase + it * 4 + wave;
        int nc = (n < N) ? n : N - 1;
        float2 xv = ((const float2*)x)[nc];
        float h = xv.x * w0 + xv.y * w1;
        float ps = h * as, pd = h * ad;
#pragma unroll
        for (int off = 1; off < 8; off <<= 1) {
            ps += __shfl_xor(ps, off);
            pd += __shfl_xor(pd, off);
        }
        if (n < N) {
            unsigned d = __builtin_amdgcn_cvt_pk_fp8_f32(h, h, 0, false);
            h8a[(size_t)n * 64 + lane] = (unsigned char)d;
            if ((lane & 7) == 0) { es[n * 8 + head] = ps; ed[n * 8 + head] = pd; }
        }
    }
}

// ---------------- bucket2 (inline bucket-count scan) ----------------

__global__ __launch_bounds__(256) void bucket2_k(const unsigned* __restrict__ barr,
                                                 const int* __restrict__ bcnt,
                                                 int* __restrict__ offsets,
                                                 int* __restrict__ esrc,
                                                 int N, int EA, int nbuck) {
    __shared__ int sd[256];
    __shared__ int bb[256];
    __shared__ int cur[256];
    int b = blockIdx.x, tid = threadIdx.x;
    int v = (tid < nbuck) ? bcnt[tid] : 0;
    sd[tid] = v;
    __syncthreads();
    for (int off = 1; off < 256; off <<= 1) {
        int t = (tid >= off) ? sd[tid - off] : 0;
        __syncthreads();
        sd[tid] += t;
        __syncthreads();
    }
    bb[tid] = sd[tid] - v;
    __syncthreads();
    int bbase = bb[b];
    if (b == 0 && tid == 0) offsets[N] = EA;
    if (b == 0 && tid < 8) esrc[EA + tid] = 0;  // pad for slot over-read

    int cnt = bcnt[b];
    const unsigned* arr = barr + (size_t)b * BSTRIDE;
    sd[tid] = 0;
    __syncthreads();
    for (int i = tid; i < cnt; i += 256)
        atomicAdd(&sd[(arr[i] >> 16) & 0xff], 1);
    __syncthreads();
    v = sd[tid];
    for (int off = 1; off < 256; off <<= 1) {
        int t = (tid >= off) ? sd[tid - off] : 0;
        __syncthreads();
        sd[tid] += t;
        __syncthreads();
    }
    int base = bbase + sd[tid] - v;
    int n = b * 256 + tid;
    if (n < N) offsets[n] = base;
    cur[tid] = base;
    __syncthreads();
    for (int i = tid; i < cnt; i += 256) {
        unsigned e = arr[i];
        int pos = atomicAdd(&cur[(e >> 16) & 0xff], 1);
        esrc[pos] = (int)(e & 0xffffu);
    }
}

// ---------------- fused GAT + MFMA GEMM ----------------
// The GEMM is row-local (h_out[n] = a16[n] @ W), so one block can: (1) run
// gat for its 64 nodes (8 passes of 8 nodes), writing bf16 activation rows
// to global (stays in the CU's L1/L2); (2) __syncthreads; (3) run the MFMA
// GEMM on those same 64 rows. No cross-block dependency -> no grid sync.
// es/ed/h8 are multi-buffered by the caller (mfma writes NEXT layer's
// buffers while other blocks' gat still reads this layer's).

template <int NCOL, bool ELU>
__global__ __launch_bounds__(256) void gatmfma_k(
    const unsigned char* __restrict__ hsrc, const float* __restrict__ es_in,
    const float* __restrict__ ed_in, const int* __restrict__ offsets,
    const int* __restrict__ esrc, const float* __restrict__ bias,
    unsigned short* __restrict__ a16, const unsigned short* __restrict__ Wt,
    const float* __restrict__ a_s, const float* __restrict__ a_d,
    unsigned char* __restrict__ h8_out, float* __restrict__ es_out,
    float* __restrict__ ed_out, int n_nodes) {
    constexpr int UPL = NCOL / 16;
    __shared__ float Cl[64 * 132];
    int wave = threadIdx.x >> 6, lane = threadIdx.x & 63;
    int rbase = blockIdx.x * 64;

    // ---- gat phase: 2 nodes/wave, 4 slots x 8 lanes (lane = head) ----
    int half = lane >> 5;
    int hl = lane & 31;
    int slot = hl >> 3;
    int l = lane & 7;
    for (int pass = 0; pass < 8; ++pass) {
        int n = rbase + pass * 8 + wave * 2 + half;
        bool valid = (n < n_nodes);
        int nc = valid ? n : 0;
        float edn = ed_in[nc * 8 + l];
        int start = valid ? offsets[nc] : 0;
        int end = valid ? offsets[nc + 1] : 0;

        v2f acc2[UPL];
#pragma unroll
        for (int k = 0; k < UPL; ++k) acc2[k] = (v2f){0.f, 0.f};
        float s = 0.f;

        for (int j = start; j < end; j += 4) {
            int jj = j + slot;
            bool act = (jj < end);
            int src = esrc[jj];
            float e0 = es_in[(size_t)src * 8 + l] + edn;
            float e = fmaxf(e0, 0.2f * e0);
            float p = act ? __expf(e) : 0.f;
            s += p;
            v2f p2 = (v2f){p, p};
            if constexpr (NCOL == 128) {
                uint4 u = *(const uint4*)(hsrc + (size_t)src * 128 + 16 * l);
                acc2[0] += p2 * (v2f)__builtin_amdgcn_cvt_pk_f32_fp8(u.x, false);
                acc2[1] += p2 * (v2f)__builtin_amdgcn_cvt_pk_f32_fp8(u.x, true);
                acc2[2] += p2 * (v2f)__builtin_amdgcn_cvt_pk_f32_fp8(u.y, false);
                acc2[3] += p2 * (v2f)__builtin_amdgcn_cvt_pk_f32_fp8(u.y, true);
                acc2[4] += p2 * (v2f)__builtin_amdgcn_cvt_pk_f32_fp8(u.z, false);
                acc2[5] += p2 * (v2f)__builtin_amdgcn_cvt_pk_f32_fp8(u.z, true);
                acc2[6] += p2 * (v2f)__builtin_amdgcn_cvt_pk_f32_fp8(u.w, false);
                acc2[7] += p2 * (v2f)__builtin_amdgcn_cvt_pk_f32_fp8(u.w, true);
            } else {
                uint2 u = *(const uint2*)(hsrc + (size_t)src * 64 + 8 * l);
                acc2[0] += p2 * (v2f)__builtin_amdgcn_cvt_pk_f32_fp8(u.x, false);
                acc2[1] += p2 * (v2f)__builtin_amdgcn_cvt_pk_f32_fp8(u.x, true);
                acc2[2] += p2 * (v2f)__builtin_amdgcn_cvt_pk_f32_fp8(u.y, false);
                acc2[3] += p2 * (v2f)__builtin_amdgcn_cvt_pk_f32_fp8(u.y, true);
            }
        }

        s += __shfl_xor(s, 8);
        s += __shfl_xor(s, 16);
        float v[2 * UPL];
#pragma unroll
        for (int k = 0; k < UPL; ++k) { v[2 * k] = acc2[k].x; v[2 * k + 1] = acc2[k].y; }
#pragma unroll
        for (int k = 0; k < 2 * UPL; ++k) {
            v[k] += __shfl_xor(v[k], 8);
            v[k] += __shfl_xor(v[k], 16);
        }

        if (slot == 0 && valid) {
            float r = 1.f / (s + 1e-16f);
#pragma unroll
            for (int k = 0; k < 2 * UPL; ++k) {
                float b = bias[(2 * UPL) * l + k];
                float t = v[k] * r + b;
                if constexpr (ELU) t = (t > 0.f) ? t : expm1f(t);
                v[k] = t;
            }
            if constexpr (NCOL == 128) {
                uint4* op = (uint4*)a16 + (size_t)n * 16 + 2 * l;
                op[0] = make_uint4(bf16pair(v[0], v[1]), bf16pair(v[2], v[3]),
                                   bf16pair(v[4], v[5]), bf16pair(v[6], v[7]));
                op[1] = make_uint4(bf16pair(v[8], v[9]), bf16pair(v[10], v[11]),
                                   bf16pair(v[12], v[13]), bf16pair(v[14], v[15]));
            } else {
                ((uint4*)a16)[(size_t)n * 8 + l] =
                    make_uint4(bf16pair(v[0], v[1]), bf16pair(v[2], v[3]),
                               bf16pair(v[4], v[5]), bf16pair(v[6], v[7]));
            }
        }
    }

    __threadfence_block();
    __syncthreads();   // block's a16 rows visible (same-CU L1/L2)

    // ---- mfma phase on this block's 64 rows ----
    constexpr int KSTEPS = NCOL / 32;
    int q = lane >> 4, m = lane & 15;
    floatx4 acc[8];
#pragma unroll
    for (int ct = 0; ct < 8; ++ct) acc[ct] = (floatx4){0.f, 0.f, 0.f, 0.f};

    int ra = rbase + wave * 16 + m;
    if (ra >= n_nodes) ra = n_nodes - 1;
    const unsigned short* arow = a16 + (size_t)ra * NCOL + q * 8;

#pragma unroll
    for (int ks = 0; ks < KSTEPS; ++ks) {
        bf16x8 af = *(const bf16x8*)(arow + ks * 32);
        const unsigned short* wp = Wt + ((size_t)(ks * 8) * 64 + lane) * 8;
#pragma unroll
        for (int ct = 0; ct < 8; ++ct) {
            bf16x8 bf = *(const bf16x8*)(wp + (size_t)ct * 64 * 8);
            acc[ct] = __builtin_amdgcn_mfma_f32_16x16x32_bf16(af, bf, acc[ct], 0, 0, 0);
        }
    }

#pragma unroll
    for (int ct = 0; ct < 8; ++ct)
#pragma unroll
        for (int i = 0; i < 4; ++i)
            Cl[(wave * 16 + q * 4 + i) * 132 + ct * 16 + m] = acc[ct][i];
    __syncthreads();

    int rl = threadIdx.x >> 2, part = threadIdx.x & 3;
    int r = rbase + rl;
    if (r < n_nodes) {
        const float* cp = &Cl[rl * 132 + part * 32];
        float e0s = 0.f, e0d = 0.f, e1s = 0.f, e1d = 0.f;
#pragma unroll
        for (int c = 0; c < 16; ++c) {
            float vv = cp[c];
            int ai = part * 32 + c;
            e0s += vv * a_s[ai];
            e0d += vv * a_d[ai];
        }
#pragma unroll
        for (int c = 16; c < 32; ++c) {
            float vv = cp[c];
            int ai = part * 32 + c;
            e1s += vv * a_s[ai];
            e1d += vv * a_d[ai];
        }
        unsigned pk8[8];
#pragma unroll
        for (int u = 0; u < 8; ++u) {
            unsigned d = __builtin_amdgcn_cvt_pk_fp8_f32(cp[4 * u], cp[4 * u + 1], 0, false);
            d = __builtin_amdgcn_cvt_pk_fp8_f32(cp[4 * u + 2], cp[4 * u + 3], d, true);
            pk8[u] = d;
        }
        uint4* hp = (uint4*)(h8_out + (size_t)r * 128) + part * 2;
        hp[0] = make_uint4(pk8[0], pk8[1], pk8[2], pk8[3]);
        hp[1] = make_uint4(pk8[4], pk8[5], pk8[6], pk8[7]);
        es_out[r * 8 + 2 * part] = e0s;
        es_out[r * 8 + 2 * part + 1] = e1s;
        ed_out[r * 8 + 2 * part] = e0d;
        ed_out[r * 8 + 2 * part + 1] = e1d;
    }
}

// ---------------- GAT layer 3 + fused mean pool ----------------

__global__ __launch_bounds__(256) void gatpool_k(
    const unsigned char* __restrict__ hsrc, const float* __restrict__ es,
    const float* __restrict__ ed, const int* __restrict__ offsets,
    const int* __restrict__ esrc, const float* __restrict__ bias,
    const int* __restrict__ batch, float* __restrict__ sums,
    float* __restrict__ cnt, int n_nodes) {
    constexpr int UPL = 8;
    __shared__ float vbuf[8 * 128];
    int wave = threadIdx.x >> 6, lane = threadIdx.x & 63;
    int half = lane >> 5;
    int hl = lane & 31;
    int slot = hl >> 3;
    int l = lane & 7;
    int ni = wave * 2 + half;
    int n = blockIdx.x * 8 + ni;
    bool valid = (n < n_nodes);
    int nc = valid ? n : 0;
    float edn = ed[nc * 8 + l];
    int start = valid ? offsets[nc] : 0;
    int end = valid ? offsets[nc + 1] : 0;

    v2f acc2[UPL];
#pragma unroll
    for (int k = 0; k < UPL; ++k) acc2[k] = (v2f){0.f, 0.f};
    float s = 0.f;

    for (int j = start; j < end; j += 4) {
        int jj = j + slot;
        bool act = (jj < end);
        int src = esrc[jj];
        float e0 = es[(size_t)src * 8 + l] + edn;
        float e = fmaxf(e0, 0.2f * e0);
        float p = act ? __expf(e) : 0.f;
        s += p;
        v2f p2 = (v2f){p, p};
        uint4 u = *(const uint4*)(hsrc + (size_t)src * 128 + 16 * l);
        acc2[0] += p2 * (v2f)__builtin_amdgcn_cvt_pk_f32_fp8(u.x, false);
        acc2[1] += p2 * (v2f)__builtin_amdgcn_cvt_pk_f32_fp8(u.x, true);
        acc2[2] += p2 * (v2f)__builtin_amdgcn_cvt_pk_f32_fp8(u.y, false);
        acc2[3] += p2 * (v2f)__builtin_amdgcn_cvt_pk_f32_fp8(u.y, true);
        acc2[4] += p2 * (v2f)__builtin_amdgcn_cvt_pk_f32_fp8(u.z, false);
        acc2[5] += p2 * (v2f)__builtin_amdgcn_cvt_pk_f32_fp8(u.z, true);
        acc2[6] += p2 * (v2f)__builtin_amdgcn_cvt_pk_f32_fp8(u.w, false);
        acc2[7] += p2 * (v2f)__builtin_amdgcn_cvt_pk_f32_fp8(u.w, true);
    }

    s += __shfl_xor(s, 8);
    s += __shfl_xor(s, 16);
    float v[16];
#pragma unroll
    for (int k = 0; k < UPL; ++k) { v[2 * k] = acc2[k].x; v[2 * k + 1] = acc2[k].y; }
#pragma unroll
    for (int k = 0; k < 16; ++k) {
        v[k] += __shfl_xor(v[k], 8);
        v[k] += __shfl_xor(v[k], 16);
    }

    if (slot == 0 && valid) {
        float r = 1.f / (s + 1e-16f);
#pragma unroll
        for (int k = 0; k < 16; ++k)
            vbuf[ni * 128 + 16 * l + k] = v[k] * r + bias[16 * l + k];
    }

    __syncthreads();
    int c = threadIdx.x;
    if (c < 128) {
        float acc = 0.f, cacc = 0.f;
        int gprev = -1;
        for (int k = 0; k < 8; ++k) {
            int nn = blockIdx.x * 8 + k;
            if (nn >= n_nodes) break;
            int g = batch[nn];
            if (g != gprev) {
                if (gprev >= 0) {
                    atomicAdd(&sums[gprev * 128 + c], acc);
                    if (c == 0) atomicAdd(&cnt[gprev], cacc);
                }
                acc = 0.f; cacc = 0.f; gprev = g;
            }
            acc += vbuf[k * 128 + c];
            cacc += 1.f;
        }
        if (gprev >= 0) {
            atomicAdd(&sums[gprev * 128 + c], acc);
            if (c == 0) atomicAdd(&cnt[gprev], cacc);
        }
    }
}

// ---------------- FC head + log_softmax ----------------

__global__ __launch_bounds__(64) void fc_k(const float* __restrict__ sums,
                                           const float* __restrict__ cnt,
                                           const float* __restrict__ fc1W,
                                           const float* __restrict__ fc1b,
                                           const float* __restrict__ fc2W,
                                           const float* __restrict__ fc2b,
                                           float* __restrict__ out) {
    int g = blockIdx.x, lane = threadIdx.x;
    __shared__ float p[128];
    __shared__ float z[32];
    __shared__ float logits[10];
    float inv = 1.f / fmaxf(cnt[g], 1.f);
    p[lane] = sums[g * 128 + lane] * inv;
    p[lane + 64] = sums[g * 128 + 64 + lane] * inv;
    __syncthreads();
    if (lane < 32) {
        float a = fc1b[lane];
        for (int k = 0; k < 128; k++) a += p[k] * fc1W[k * 32 + lane];
        z[lane] = fmaxf(a, 0.f);
    }
    __syncthreads();
    if (lane < 10) {
        float a = fc2b[lane];
        for (int k = 0; k < 32; k++) a += z[k] * fc2W[k * 10 + lane];
        logits[lane] = a;
    }
    __syncthreads();
    if (lane < 10) {
        float mx = logits[0];
#pragma unroll
        for (int i = 1; i < 10; i++) mx = fmaxf(mx, logits[i]);
        float se = 0.f;
#pragma unroll
        for (int i = 0; i < 10; i++) se += __expf(logits[i] - mx);
        out[g * 10 + lane] = logits[lane] - mx - logf(se);
    }
}

// ---------------- launch ----------------

extern "C" void kernel_launch(void* const* d_in, const int* in_sizes, int n_in,
                              void* d_out, int out_size, void* d_ws, size_t ws_size,
                              hipStream_t stream) {
    const float* x = (const float*)d_in[0];
    const int* edge = (const int*)d_in[1];
    const int* batch = (const int*)d_in[2];
    const float* W1 = (const float*)d_in[3];
    const float* a1s = (const float*)d_in[4];
    const float* a1d = (const float*)d_in[5];
    const float* b1 = (const float*)d_in[6];
    const float* W2 = (const float*)d_in[7];
    const float* a2s = (const float*)d_in[8];
    const float* a2d = (const float*)d_in[9];
    const float* b2 = (const float*)d_in[10];
    const float* W3 = (const float*)d_in[11];
    const float* a3s = (const float*)d_in[12];
    const float* a3d = (const float*)d_in[13];
    const float* b3 = (const float*)d_in[14];
    const float* fc1W = (const float*)d_in[15];
    const float* fc1b = (const float*)d_in[16];
    const float* fc2W = (const float*)d_in[17];
    const float* fc2b = (const float*)d_in[18];
    float* out = (float*)d_out;

    const int N = in_sizes[0] / 2;   // 50000
    const int E = in_sizes[1] / 2;   // 800000
    const int EA = E + N;
    const int NG = out_size / 10;    // 512
    const int NBUCK = (N + 255) >> 8;
    const int B1 = (EA + 4095) / 4096;
    const int G1 = (N + 31) / 32;

    char* p = (char*)d_ws;
    unsigned char* h8b = (unsigned char*)p; p += (size_t)N * 128;  // layer2 fp8 h
    // h8c (layer3 fp8 h, N*128) aliases [h8a (N*64) + a16a (N*128)] — both
    // dead once gatmfma<64> (K2) completes; K3 reads only h8b/a16b.
    unsigned char* h8a = (unsigned char*)p;
    unsigned char* h8c = (unsigned char*)p;
    p += (size_t)N * 64;
    unsigned short* a16a = (unsigned short*)p; p += (size_t)N * 64 * 2;
    unsigned short* a16b = (unsigned short*)p; p += (size_t)N * 128 * 2;
    unsigned short* Wt2 = (unsigned short*)p; p += (size_t)64 * 128 * 2;
    unsigned short* Wt3 = (unsigned short*)p; p += (size_t)128 * 128 * 2;
    float* esa = (float*)p; p += (size_t)N * 8 * 4;
    float* eda = (float*)p; p += (size_t)N * 8 * 4;
    float* esb = (float*)p; p += (size_t)N * 8 * 4;
    float* edb = (float*)p; p += (size_t)N * 8 * 4;
    float* esc = esa;  // dead after K2's gat phase completes (K3 reads esb)
    float* edc = eda;
    // sums, cnt, bcnt contiguous: zeroed by ONE memset
    float* sums = (float*)p; p += (size_t)NG * 128 * 4;
    float* cnt = (float*)p;  p += (size_t)NG * 4;
    int* bcnt = (int*)p;     p += 256 * 4;
    int* offsets = (int*)p;  p += (size_t)(N + 1) * 4;
    int* esrc = (int*)p;     p += (size_t)(EA + 8) * 4;
    unsigned* barr = (unsigned*)p; p += (size_t)NBUCK * BSTRIDE * 4;

    hipMemsetAsync(sums, 0, ((size_t)NG * 128 + NG + 256) * 4, stream);

    prep_k<<<B1 + 96 + G1, 256, 0, stream>>>(
        edge, barr, bcnt, E, EA, B1, W2, Wt2, W3, Wt3,
        x, W1, a1s, a1d, h8a, esa, eda, N);
    bucket2_k<<<NBUCK, 256, 0, stream>>>(barr, bcnt, offsets, esrc, N, EA, NBUCK);

    int fblocks = (N + 63) / 64;
    gatmfma_k<64, true><<<fblocks, 256, 0, stream>>>(
        h8a, esa, eda, offsets, esrc, b1, a16a, Wt2, a2s, a2d, h8b, esb, edb, N);
    gatmfma_k<128, true><<<fblocks, 256, 0, stream>>>(
        h8b, esb, edb, offsets, esrc, b2, a16b, Wt3, a3s, a3d, h8c, esc, edc, N);
    gatpool_k<<<(N + 7) / 8, 256, 0, stream>>>(
        h8c, esc, edc, offsets, esrc, b3, batch, sums, cnt, N);

    fc_k<<<NG, 64, 0, stream>>>(sums, cnt, fc1W, fc1b, fc2W, fc2b, out);
}

// Round 18
// 263.386 us; speedup vs baseline: 1.5344x; 1.5344x over previous
//
#include <hip/hip_runtime.h>
#include <cstddef>
#include <cstdint>

typedef __attribute__((ext_vector_type(8))) short bf16x8;
typedef __attribute__((ext_vector_type(4))) float floatx4;
typedef __attribute__((ext_vector_type(2))) float v2f;

#define BSTRIDE 8192

// ---------------- pack helpers ----------------

__device__ __forceinline__ unsigned bf16pair(float a, float b) {
    unsigned ua = __float_as_uint(a), ub = __float_as_uint(b);
    ua += 0x7fffu + ((ua >> 16) & 1u);   // RNE
    ub += 0x7fffu + ((ub >> 16) & 1u);
    return (ua >> 16) | (ub & 0xffff0000u);
}
__device__ __forceinline__ unsigned short bf16one(float a) {
    unsigned ua = __float_as_uint(a);
    ua += 0x7fffu + ((ua >> 16) & 1u);
    return (unsigned short)(ua >> 16);
}

// ---------------- prep: bucket1 + wconv(W2,W3) + gemm1 (grid-split) ----------------

__global__ __launch_bounds__(256) void prep_k(
    const int* __restrict__ edge, unsigned* __restrict__ barr,
    int* __restrict__ bcnt, int E, int EA, int B1,
    const float* __restrict__ W2, unsigned short* __restrict__ Wt2,
    const float* __restrict__ W3, unsigned short* __restrict__ Wt3,
    const float* __restrict__ x, const float* __restrict__ W1,
    const float* __restrict__ a1s, const float* __restrict__ a1d,
    unsigned char* __restrict__ h8a, float* __restrict__ es,
    float* __restrict__ ed, int N) {
    int tid = threadIdx.x;
    if ((int)blockIdx.x < B1) {
        __shared__ int h[256];
        __shared__ int lbase[256];
        h[tid] = 0;
        __syncthreads();
        int start = blockIdx.x * 4096;
        unsigned ent[16];
        int lp[16];
#pragma unroll
        for (int k = 0; k < 16; ++k) {
            int i = start + k * 256 + tid;
            if (i < EA) {
                int s, d;
                if (i < E) { s = edge[i]; d = edge[E + i]; }
                else { s = i - E; d = s; }
                int b = d >> 8;
                ent[k] = (unsigned)s | ((unsigned)(d & 255) << 16) | ((unsigned)b << 24);
                lp[k] = atomicAdd(&h[b], 1);
            } else {
                ent[k] = 0xffffffffu;
                lp[k] = 0;
            }
        }
        __syncthreads();
        lbase[tid] = h[tid] ? atomicAdd(&bcnt[tid], h[tid]) : 0;
        __syncthreads();
#pragma unroll
        for (int k = 0; k < 16; ++k) {
            if (ent[k] != 0xffffffffu) {
                int b = ent[k] >> 24;
                int pos = lbase[b] + lp[k];
                if (pos < BSTRIDE)
                    barr[(size_t)b * BSTRIDE + pos] = ent[k] & 0x00ffffffu;
            }
        }
        return;
    }
    if ((int)blockIdx.x < B1 + 96) {
        int rel = blockIdx.x - B1;
        const float* W = (rel < 32) ? W2 : W3;
        unsigned short* Wt = (rel < 32) ? Wt2 : Wt3;
        int total = (rel < 32) ? 8192 : 16384;
        int o = ((rel < 32) ? rel : rel - 32) * 256 + tid;
        if (o < total) {
            int j = o & 7, lane = (o >> 3) & 63, ct = (o >> 9) & 7, ks = o >> 12;
            int k = ks * 32 + (lane >> 4) * 8 + j;
            int n = ct * 16 + (lane & 15);
            Wt[o] = bf16one(W[k * 128 + n]);
        }
        return;
    }
    int wave = tid >> 6, lane = tid & 63;
    int nbase = (blockIdx.x - B1 - 96) * 32;
    float w0 = W1[lane], w1 = W1[64 + lane];
    float as = a1s[lane], ad = a1d[lane];
    int head = lane >> 3;
#pragma unroll
    for (int it = 0; it < 8; ++it) {
        int n = nbase + it * 4 + wave;
        int nc = (n < N) ? n : N - 1;
        float2 xv = ((const float2*)x)[nc];
        float h = xv.x * w0 + xv.y * w1;
        float ps = h * as, pd = h * ad;
#pragma unroll
        for (int off = 1; off < 8; off <<= 1) {
            ps += __shfl_xor(ps, off);
            pd += __shfl_xor(pd, off);
        }
        if (n < N) {
            unsigned d = __builtin_amdgcn_cvt_pk_fp8_f32(h, h, 0, false);
            h8a[(size_t)n * 64 + lane] = (unsigned char)d;
            if ((lane & 7) == 0) { es[n * 8 + head] = ps; ed[n * 8 + head] = pd; }
        }
    }
}

// ---------------- bucket2 (inline bucket-count scan) ----------------

__global__ __launch_bounds__(256) void bucket2_k(const unsigned* __restrict__ barr,
                                                 const int* __restrict__ bcnt,
                                                 int* __restrict__ offsets,
                                                 int* __restrict__ esrc,
                                                 int N, int EA, int nbuck) {
    __shared__ int sd[256];
    __shared__ int bb[256];
    __shared__ int cur[256];
    int b = blockIdx.x, tid = threadIdx.x;
    int v = (tid < nbuck) ? bcnt[tid] : 0;
    sd[tid] = v;
    __syncthreads();
    for (int off = 1; off < 256; off <<= 1) {
        int t = (tid >= off) ? sd[tid - off] : 0;
        __syncthreads();
        sd[tid] += t;
        __syncthreads();
    }
    bb[tid] = sd[tid] - v;
    __syncthreads();
    int bbase = bb[b];
    if (b == 0 && tid == 0) offsets[N] = EA;
    if (b == 0 && tid < 8) esrc[EA + tid] = 0;  // pad for slot over-read

    int cnt = bcnt[b];
    const unsigned* arr = barr + (size_t)b * BSTRIDE;
    sd[tid] = 0;
    __syncthreads();
    for (int i = tid; i < cnt; i += 256)
        atomicAdd(&sd[(arr[i] >> 16) & 0xff], 1);
    __syncthreads();
    v = sd[tid];
    for (int off = 1; off < 256; off <<= 1) {
        int t = (tid >= off) ? sd[tid - off] : 0;
        __syncthreads();
        sd[tid] += t;
        __syncthreads();
    }
    int base = bbase + sd[tid] - v;
    int n = b * 256 + tid;
    if (n < N) offsets[n] = base;
    cur[tid] = base;
    __syncthreads();
    for (int i = tid; i < cnt; i += 256) {
        unsigned e = arr[i];
        int pos = atomicAdd(&cur[(e >> 16) & 0xff], 1);
        esrc[pos] = (int)(e & 0xffffu);
    }
}

// ---------------- layers 2/3: MFMA GEMM + scores (fp8 h out) ----------------

template <int IN>
__global__ __launch_bounds__(256) void gemm_mfma_k(
    const unsigned short* __restrict__ a16, const unsigned short* __restrict__ Wt,
    const float* __restrict__ a_s, const float* __restrict__ a_d,
    unsigned char* __restrict__ h8, float* __restrict__ es, float* __restrict__ ed,
    int n_nodes) {
    constexpr int KSTEPS = IN / 32;
    __shared__ float Cl[64 * 132];
    int wave = threadIdx.x >> 6, lane = threadIdx.x & 63;
    int q = lane >> 4, m = lane & 15;
    int rbase = blockIdx.x * 64;

    floatx4 acc[8];
#pragma unroll
    for (int ct = 0; ct < 8; ++ct) acc[ct] = (floatx4){0.f, 0.f, 0.f, 0.f};

    int ra = rbase + wave * 16 + m;
    if (ra >= n_nodes) ra = n_nodes - 1;
    const unsigned short* arow = a16 + (size_t)ra * IN + q * 8;

#pragma unroll
    for (int ks = 0; ks < KSTEPS; ++ks) {
        bf16x8 af = *(const bf16x8*)(arow + ks * 32);
        const unsigned short* wp = Wt + ((size_t)(ks * 8) * 64 + lane) * 8;
#pragma unroll
        for (int ct = 0; ct < 8; ++ct) {
            bf16x8 bf = *(const bf16x8*)(wp + (size_t)ct * 64 * 8);
            acc[ct] = __builtin_amdgcn_mfma_f32_16x16x32_bf16(af, bf, acc[ct], 0, 0, 0);
        }
    }

#pragma unroll
    for (int ct = 0; ct < 8; ++ct)
#pragma unroll
        for (int i = 0; i < 4; ++i)
            Cl[(wave * 16 + q * 4 + i) * 132 + ct * 16 + m] = acc[ct][i];
    __syncthreads();

    int rl = threadIdx.x >> 2, part = threadIdx.x & 3;
    int r = rbase + rl;
    if (r < n_nodes) {
        const float* cp = &Cl[rl * 132 + part * 32];
        float e0s = 0.f, e0d = 0.f, e1s = 0.f, e1d = 0.f;
#pragma unroll
        for (int c = 0; c < 16; ++c) {
            float v = cp[c];
            int ai = part * 32 + c;
            e0s += v * a_s[ai];
            e0d += v * a_d[ai];
        }
#pragma unroll
        for (int c = 16; c < 32; ++c) {
            float v = cp[c];
            int ai = part * 32 + c;
            e1s += v * a_s[ai];
            e1d += v * a_d[ai];
        }
        unsigned pk8[8];
#pragma unroll
        for (int u = 0; u < 8; ++u) {
            unsigned d = __builtin_amdgcn_cvt_pk_fp8_f32(cp[4 * u], cp[4 * u + 1], 0, false);
            d = __builtin_amdgcn_cvt_pk_fp8_f32(cp[4 * u + 2], cp[4 * u + 3], d, true);
            pk8[u] = d;
        }
        uint4* hp = (uint4*)(h8 + (size_t)r * 128) + part * 2;
        hp[0] = make_uint4(pk8[0], pk8[1], pk8[2], pk8[3]);
        hp[1] = make_uint4(pk8[4], pk8[5], pk8[6], pk8[7]);
        es[r * 8 + 2 * part] = e0s;
        es[r * 8 + 2 * part + 1] = e1s;
        ed[r * 8 + 2 * part] = e0d;
        ed[r * 8 + 2 * part + 1] = e1d;
    }
}

// ---------------- GAT: 2 nodes/wave, 4 slots x 8 lanes; lane = head ----------------
// POOL (layer 3): stage the block's 8 node outputs in LDS, then run-length
// flush per distinct graph (batch sorted). Otherwise write packed bf16.
// unroll 2 on the edge loop: two independent 4-edge steps in flight.

template <int NCOL, bool ELU, bool POOL>
__global__ __launch_bounds__(256) void gat_k(
    const unsigned char* __restrict__ hsrc, const float* __restrict__ es,
    const float* __restrict__ ed, const int* __restrict__ offsets,
    const int* __restrict__ esrc, const float* __restrict__ bias,
    void* __restrict__ outp, const int* __restrict__ batch,
    float* __restrict__ sums, float* __restrict__ cnt, int n_nodes) {
    constexpr int UPL = NCOL / 16;
    __shared__ float vbuf[POOL ? 8 * 128 : 1];
    int wave = threadIdx.x >> 6, lane = threadIdx.x & 63;
    int half = lane >> 5;
    int hl = lane & 31;
    int slot = hl >> 3;
    int l = lane & 7;
    int ni = wave * 2 + half;
    int n = blockIdx.x * 8 + ni;
    bool valid = (n < n_nodes);
    int nc = valid ? n : 0;
    float edn = ed[nc * 8 + l];
    int start = valid ? offsets[nc] : 0;
    int end = valid ? offsets[nc + 1] : 0;

    v2f acc2[UPL];
#pragma unroll
    for (int k = 0; k < UPL; ++k) acc2[k] = (v2f){0.f, 0.f};
    float s = 0.f;

#pragma unroll 2
    for (int j = start; j < end; j += 4) {
        int jj = j + slot;
        bool act = (jj < end);
        int src = esrc[jj];
        float e0 = es[(size_t)src * 8 + l] + edn;
        float e = fmaxf(e0, 0.2f * e0);
        float p = act ? __expf(e) : 0.f;
        s += p;
        v2f p2 = (v2f){p, p};
        if constexpr (NCOL == 128) {
            uint4 u = *(const uint4*)(hsrc + (size_t)src * 128 + 16 * l);
            acc2[0] += p2 * (v2f)__builtin_amdgcn_cvt_pk_f32_fp8(u.x, false);
            acc2[1] += p2 * (v2f)__builtin_amdgcn_cvt_pk_f32_fp8(u.x, true);
            acc2[2] += p2 * (v2f)__builtin_amdgcn_cvt_pk_f32_fp8(u.y, false);
            acc2[3] += p2 * (v2f)__builtin_amdgcn_cvt_pk_f32_fp8(u.y, true);
            acc2[4] += p2 * (v2f)__builtin_amdgcn_cvt_pk_f32_fp8(u.z, false);
            acc2[5] += p2 * (v2f)__builtin_amdgcn_cvt_pk_f32_fp8(u.z, true);
            acc2[6] += p2 * (v2f)__builtin_amdgcn_cvt_pk_f32_fp8(u.w, false);
            acc2[7] += p2 * (v2f)__builtin_amdgcn_cvt_pk_f32_fp8(u.w, true);
        } else {
            uint2 u = *(const uint2*)(hsrc + (size_t)src * 64 + 8 * l);
            acc2[0] += p2 * (v2f)__builtin_amdgcn_cvt_pk_f32_fp8(u.x, false);
            acc2[1] += p2 * (v2f)__builtin_amdgcn_cvt_pk_f32_fp8(u.x, true);
            acc2[2] += p2 * (v2f)__builtin_amdgcn_cvt_pk_f32_fp8(u.y, false);
            acc2[3] += p2 * (v2f)__builtin_amdgcn_cvt_pk_f32_fp8(u.y, true);
        }
    }

    s += __shfl_xor(s, 8);
    s += __shfl_xor(s, 16);
    float v[2 * UPL];
#pragma unroll
    for (int k = 0; k < UPL; ++k) { v[2 * k] = acc2[k].x; v[2 * k + 1] = acc2[k].y; }
#pragma unroll
    for (int k = 0; k < 2 * UPL; ++k) {
        v[k] += __shfl_xor(v[k], 8);
        v[k] += __shfl_xor(v[k], 16);
    }

    if (slot == 0 && valid) {
        float r = 1.f / (s + 1e-16f);
#pragma unroll
        for (int k = 0; k < 2 * UPL; ++k) {
            float b = bias[(2 * UPL) * l + k];
            float t = v[k] * r + b;
            if constexpr (ELU) t = (t > 0.f) ? t : expm1f(t);
            v[k] = t;
        }
        if constexpr (POOL) {
#pragma unroll
            for (int k = 0; k < 2 * UPL; ++k)
                vbuf[ni * 128 + (2 * UPL) * l + k] = v[k];
        } else if constexpr (NCOL == 128) {
            uint4* op = (uint4*)outp + (size_t)n * 16 + 2 * l;
            op[0] = make_uint4(bf16pair(v[0], v[1]), bf16pair(v[2], v[3]),
                               bf16pair(v[4], v[5]), bf16pair(v[6], v[7]));
            op[1] = make_uint4(bf16pair(v[8], v[9]), bf16pair(v[10], v[11]),
                               bf16pair(v[12], v[13]), bf16pair(v[14], v[15]));
        } else {
            ((uint4*)outp)[(size_t)n * 8 + l] =
                make_uint4(bf16pair(v[0], v[1]), bf16pair(v[2], v[3]),
                           bf16pair(v[4], v[5]), bf16pair(v[6], v[7]));
        }
    }

    if constexpr (POOL) {
        __syncthreads();
        int c = threadIdx.x;
        if (c < 128) {
            float acc = 0.f, cacc = 0.f;
            int gprev = -1;
            for (int k = 0; k < 8; ++k) {
                int nn = blockIdx.x * 8 + k;
                if (nn >= n_nodes) break;
                int g = batch[nn];
                if (g != gprev) {
                    if (gprev >= 0) {
                        atomicAdd(&sums[gprev * 128 + c], acc);
                        if (c == 0) atomicAdd(&cnt[gprev], cacc);
                    }
                    acc = 0.f; cacc = 0.f; gprev = g;
                }
                acc += vbuf[k * 128 + c];
                cacc += 1.f;
            }
            if (gprev >= 0) {
                atomicAdd(&sums[gprev * 128 + c], acc);
                if (c == 0) atomicAdd(&cnt[gprev], cacc);
            }
        }
    }
}

// ---------------- FC head + log_softmax ----------------

__global__ __launch_bounds__(64) void fc_k(const float* __restrict__ sums,
                                           const float* __restrict__ cnt,
                                           const float* __restrict__ fc1W,
                                           const float* __restrict__ fc1b,
                                           const float* __restrict__ fc2W,
                                           const float* __restrict__ fc2b,
                                           float* __restrict__ out) {
    int g = blockIdx.x, lane = threadIdx.x;
    __shared__ float p[128];
    __shared__ float z[32];
    __shared__ float logits[10];
    float inv = 1.f / fmaxf(cnt[g], 1.f);
    p[lane] = sums[g * 128 + lane] * inv;
    p[lane + 64] = sums[g * 128 + 64 + lane] * inv;
    __syncthreads();
    if (lane < 32) {
        float a = fc1b[lane];
        for (int k = 0; k < 128; k++) a += p[k] * fc1W[k * 32 + lane];
        z[lane] = fmaxf(a, 0.f);
    }
    __syncthreads();
    if (lane < 10) {
        float a = fc2b[lane];
        for (int k = 0; k < 32; k++) a += z[k] * fc2W[k * 10 + lane];
        logits[lane] = a;
    }
    __syncthreads();
    if (lane < 10) {
        float mx = logits[0];
#pragma unroll
        for (int i = 1; i < 10; i++) mx = fmaxf(mx, logits[i]);
        float se = 0.f;
#pragma unroll
        for (int i = 0; i < 10; i++) se += __expf(logits[i] - mx);
        out[g * 10 + lane] = logits[lane] - mx - logf(se);
    }
}

// ---------------- launch ----------------

extern "C" void kernel_launch(void* const* d_in, const int* in_sizes, int n_in,
                              void* d_out, int out_size, void* d_ws, size_t ws_size,
                              hipStream_t stream) {
    const float* x = (const float*)d_in[0];
    const int* edge = (const int*)d_in[1];
    const int* batch = (const int*)d_in[2];
    const float* W1 = (const float*)d_in[3];
    const float* a1s = (const float*)d_in[4];
    const float* a1d = (const float*)d_in[5];
    const float* b1 = (const float*)d_in[6];
    const float* W2 = (const float*)d_in[7];
    const float* a2s = (const float*)d_in[8];
    const float* a2d = (const float*)d_in[9];
    const float* b2 = (const float*)d_in[10];
    const float* W3 = (const float*)d_in[11];
    const float* a3s = (const float*)d_in[12];
    const float* a3d = (const float*)d_in[13];
    const float* b3 = (const float*)d_in[14];
    const float* fc1W = (const float*)d_in[15];
    const float* fc1b = (const float*)d_in[16];
    const float* fc2W = (const float*)d_in[17];
    const float* fc2b = (const float*)d_in[18];
    float* out = (float*)d_out;

    const int N = in_sizes[0] / 2;   // 50000
    const int E = in_sizes[1] / 2;   // 800000
    const int EA = E + N;
    const int NG = out_size / 10;    // 512
    const int NBUCK = (N + 255) >> 8;
    const int B1 = (EA + 4095) / 4096;
    const int G1 = (N + 31) / 32;

    char* p = (char*)d_ws;
    unsigned char* h8 = (unsigned char*)p; p += (size_t)N * 128;  // layers 2/3 fp8 h
    unsigned char* h8a = (unsigned char*)p; p += (size_t)N * 64;  // layer 1 fp8 h
    unsigned short* a16a = (unsigned short*)p; p += (size_t)N * 64 * 2;   // gat1 out
    unsigned short* a16b = (unsigned short*)p; p += (size_t)N * 128 * 2;  // gat2 out
    unsigned short* Wt2 = (unsigned short*)p; p += (size_t)64 * 128 * 2;
    unsigned short* Wt3 = (unsigned short*)p; p += (size_t)128 * 128 * 2;
    float* es = (float*)p;  p += (size_t)N * 8 * 4;
    float* ed = (float*)p;  p += (size_t)N * 8 * 4;
    // sums, cnt, bcnt contiguous: zeroed by ONE memset
    float* sums = (float*)p; p += (size_t)NG * 128 * 4;
    float* cnt = (float*)p;  p += (size_t)NG * 4;
    int* bcnt = (int*)p;     p += 256 * 4;
    int* offsets = (int*)p;  p += (size_t)(N + 1) * 4;
    int* esrc = (int*)p;     p += (size_t)(EA + 8) * 4;
    unsigned* barr = (unsigned*)p; p += (size_t)NBUCK * BSTRIDE * 4;

    hipMemsetAsync(sums, 0, ((size_t)NG * 128 + NG + 256) * 4, stream);

    prep_k<<<B1 + 96 + G1, 256, 0, stream>>>(
        edge, barr, bcnt, E, EA, B1, W2, Wt2, W3, Wt3,
        x, W1, a1s, a1d, h8a, es, ed, N);
    bucket2_k<<<NBUCK, 256, 0, stream>>>(barr, bcnt, offsets, esrc, N, EA, NBUCK);

    int mblocks = (N + 63) / 64;
    int ablocks = (N + 7) / 8;
    gat_k<64, true, false><<<ablocks, 256, 0, stream>>>(
        h8a, es, ed, offsets, esrc, b1, a16a, batch, sums, cnt, N);
    gemm_mfma_k<64><<<mblocks, 256, 0, stream>>>(a16a, Wt2, a2s, a2d, h8, es, ed, N);
    gat_k<128, true, false><<<ablocks, 256, 0, stream>>>(
        h8, es, ed, offsets, esrc, b2, a16b, batch, sums, cnt, N);
    gemm_mfma_k<128><<<mblocks, 256, 0, stream>>>(a16b, Wt3, a3s, a3d, h8, es, ed, N);
    gat_k<128, false, true><<<ablocks, 256, 0, stream>>>(
        h8, es, ed, offsets, esrc, b3, nullptr, batch, sums, cnt, N);

    fc_k<<<NG, 64, 0, stream>>>(sums, cnt, fc1W, fc1b, fc2W, fc2b, out);
}